// Round 21
// baseline (757.671 us; speedup 1.0000x reference)
//
#include <hip/hip_runtime.h>
#include <hip/hip_bf16.h>
#include <math.h>

#define T_TOK 2048
#define H_DIM 2048
#define E_NUM 64
#define F_DIM 512
#define K_TOP 8
#define FS_DIM 512
#define NROWS (T_TOK * K_TOP)

typedef __attribute__((ext_vector_type(8))) short short8v;   // bf16x8 MFMA frag
typedef __attribute__((ext_vector_type(4))) float f32x4;     // MFMA accum

static __device__ __forceinline__ unsigned short f2bf(float f) {
    unsigned int u = __float_as_uint(f);
    u += 0x7fff + ((u >> 16) & 1);           // RNE to bf16
    return (unsigned short)(u >> 16);
}

// B tile [128 n][64 k]: 16B-chunk XOR swizzle (proven r5/6/9-14)
#define BCHUNK(row, k8) ((((k8) ^ ((row) + ((row) >> 3)))) & 7)
// A tile rows 64 shorts (128B, bank-neutral): 8-chunk XOR (proven r9/r14)
#define ASWZ(row) (((row) + ((row) >> 3)) & 7)

typedef const unsigned int __attribute__((address_space(1))) gu32;
typedef unsigned int __attribute__((address_space(3))) lu32;
#define GLDS16(gsrc, ldst) \
    __builtin_amdgcn_global_load_lds((gu32*)(gsrc), (lu32*)(ldst), 16, 0, 0)

// ---------------------------------------------------------------------------
// x (fp32) -> bf16 copy
// ---------------------------------------------------------------------------
__global__ __launch_bounds__(256) void cvt_bf16_kernel(
    const float* __restrict__ in, unsigned short* __restrict__ out, int n8)
{
    int i = blockIdx.x * 256 + threadIdx.x;
    if (i < n8) {
        const float4* p = (const float4*)(in + (size_t)i * 8);
        float4 v0 = p[0], v1 = p[1];
        ushort4 a = make_ushort4(f2bf(v0.x), f2bf(v0.y), f2bf(v0.z), f2bf(v0.w));
        ushort4 b = make_ushort4(f2bf(v1.x), f2bf(v1.y), f2bf(v1.z), f2bf(v1.w));
        ushort4* q = (ushort4*)(out + (size_t)i * 8);
        q[0] = a; q[1] = b;
    }
}

// ---------------------------------------------------------------------------
// Router: one wave per token (fp32 math, exact top-k vs reference).
// ---------------------------------------------------------------------------
__global__ __launch_bounds__(64) void router_kernel(
    const float* __restrict__ x, const float* __restrict__ Wg,
    int* __restrict__ topk_idx, float* __restrict__ topk_w,
    float* __restrict__ sgate, int* __restrict__ counts)
{
    const int t = blockIdx.x;
    const int lane = threadIdx.x;
    const float* xr = x + (size_t)t * H_DIM;

    float a0 = 0.f, a1 = 0.f, a2 = 0.f, a3 = 0.f;
    for (int h = 0; h < H_DIM; h += 4) {
        float4 xv = *(const float4*)&xr[h];
        a0 += xv.x * Wg[(h + 0) * 65 + lane];
        a1 += xv.y * Wg[(h + 1) * 65 + lane];
        a2 += xv.z * Wg[(h + 2) * 65 + lane];
        a3 += xv.w * Wg[(h + 3) * 65 + lane];
    }
    float logit = (a0 + a1) + (a2 + a3);

    float a64 = 0.f;
    for (int h = lane; h < H_DIM; h += 64) a64 += xr[h] * Wg[h * 65 + 64];
#pragma unroll
    for (int off = 32; off >= 1; off >>= 1) a64 += __shfl_xor(a64, off);

    float v = logit;
    float selv[K_TOP]; int seli[K_TOP];
#pragma unroll
    for (int k = 0; k < K_TOP; ++k) {
        float mv = v; int mi = lane;
#pragma unroll
        for (int off = 32; off >= 1; off >>= 1) {
            float ov = __shfl_xor(mv, off);
            int   oi = __shfl_xor(mi, off);
            if (ov > mv || (ov == mv && oi < mi)) { mv = ov; mi = oi; }
        }
        selv[k] = mv; seli[k] = mi;
        if (lane == mi) v = -INFINITY;
    }

    if (lane == 0) {
        float m = selv[0];
        float w[K_TOP]; float s = 0.f;
#pragma unroll
        for (int k = 0; k < K_TOP; ++k) { w[k] = __expf(selv[k] - m); s += w[k]; }
        float inv = 1.f / s;
#pragma unroll
        for (int k = 0; k < K_TOP; ++k) {
            topk_idx[t * K_TOP + k] = seli[k];
            topk_w[t * K_TOP + k] = w[k] * inv;
            atomicAdd(&counts[seli[k]], 1);
        }
        sgate[t] = 1.f / (1.f + __expf(-a64));
    }
}

// ---------------------------------------------------------------------------
// Deterministic per-expert compaction.
// ---------------------------------------------------------------------------
__global__ __launch_bounds__(256) void bucket_kernel(
    const int* __restrict__ topk_idx, const float* __restrict__ topk_w,
    const int* __restrict__ counts, int* __restrict__ offsets,
    int* __restrict__ bucket_tok, float* __restrict__ bucket_w)
{
    const int e = blockIdx.x, thr = threadIdx.x;
    __shared__ int cnt[256];
    __shared__ int base_s;
    const int q0 = thr * 64;
    int c = 0;
    for (int q = 0; q < 64; ++q) c += (topk_idx[q0 + q] == e) ? 1 : 0;
    cnt[thr] = c;
    __syncthreads();
    if (thr == 0) {
        int off = 0;
        for (int i = 0; i < e; ++i) off += counts[i];
        offsets[e] = off;
        base_s = off;
        int run = 0;
        for (int i = 0; i < 256; ++i) { int tval = cnt[i]; cnt[i] = run; run += tval; }
    }
    __syncthreads();
    int pos = base_s + cnt[thr];
    for (int q = 0; q < 64; ++q) {
        int pp = q0 + q;
        if (topk_idx[pp] == e) {
            bucket_tok[pos] = pp >> 3;
            bucket_w[pos] = topk_w[pp];
            ++pos;
        }
    }
}

// ---------------------------------------------------------------------------
// gate_up + SiLU*u*topw — r14 fat-phase pipeline, UNIFIED grid:
// eu<64 routed expert (in-block m-loop); eu>=64 shared m-tile (eu-64).
// BM=128, BK=64 phases, 256 thr = 4 waves (2wm x 2wn); 32 MFMA/wave/phase.
// A: GLDS dbuf [2][128][64]; B: W fp32->reg->bf16 ds_write dbuf [2][128][64].
// ---------------------------------------------------------------------------
__global__ __launch_bounds__(256, 2) void gu_mfma_kernel(
    const unsigned short* __restrict__ xb,
    const float* __restrict__ Wgu, const float* __restrict__ Wsgu,
    const int* __restrict__ counts, const int* __restrict__ offsets,
    const int* __restrict__ bucket_tok, const float* __restrict__ bucket_w,
    unsigned short* __restrict__ act_r, unsigned short* __restrict__ act_s)
{
    constexpr int BM = 128;
    __shared__ __align__(16) unsigned short As[2][BM * 64];   // 2 x 16 KB
    __shared__ __align__(16) unsigned short Bs[2][128 * 64];  // 2 x 16 KB
    __shared__ int   toksS[BM];
    __shared__ float twsS[BM];

    const int tid  = threadIdx.x;
    const int lane = tid & 63;
    const int wid  = tid >> 6;                // 0..3
    const int wm = wid >> 1, wn = wid & 1;
    const int lrow = lane & 15, lhi = lane >> 4;

    // unified decode: 640 blocks = 8 colblk x 80 eu, XCD-bijective swizzle
    const int nw  = (blockIdx.x & 7) * 80 + (blockIdx.x >> 3);
    const int cblk = nw & 7;
    const int eu   = nw >> 3;                 // 0..79
    const bool sh  = (eu >= E_NUM);
    int ne, base, m0_beg, m0_end;
    const float* W;
    if (sh) {
        ne = T_TOK; base = 0;
        m0_beg = (eu - E_NUM) * BM; m0_end = m0_beg + BM;
        W = Wsgu;
    } else {
        ne = counts[eu]; base = offsets[eu];
        m0_beg = 0; m0_end = ne;
        W = Wgu + (size_t)eu * H_DIM * (2 * F_DIM);
    }
    const int c0 = cblk * 64;                 // act-col base

    // B staging: thread covers 4 n-cols x 8 k-rows (r14 geometry)
    const int n4 = (tid & 31) * 4;            // 0..124
    const int kq = (tid >> 5) * 8;            // 0..56
    const int grp = n4 >> 5;                  // {g lo,u lo,g hi,u hi}
    const int srccol = c0 + (grp >> 1) * 32 + (n4 & 31) + ((grp & 1) ? F_DIM : 0);
    int wrB[4];
#pragma unroll
    for (int cc = 0; cc < 4; ++cc) {
        int n = n4 + cc;
        wrB[cc] = n * 64 + BCHUNK(n, kq >> 3) * 8;
    }
    int rdB[4][2];
#pragma unroll
    for (int fn = 0; fn < 4; ++fn) {
        int r = wn * 64 + fn * 16 + lrow;
#pragma unroll
        for (int ks = 0; ks < 2; ++ks) {
            int kc = ks * 4 + lhi;
            rdB[fn][ks] = r * 64 + BCHUNK(r, kc) * 8;
        }
    }
    int rdA[4][2];
#pragma unroll
    for (int fm = 0; fm < 4; ++fm) {
        int arow = wm * 64 + fm * 16 + lrow;
#pragma unroll
        for (int ks = 0; ks < 2; ++ks) {
            int kc = ks * 4 + lhi;
            rdA[fm][ks] = arow * 64 + ((kc ^ ASWZ(arow)) & 7) * 8;
        }
    }
    const int NT = H_DIM / 64;

    for (int m0 = m0_beg; m0 < m0_end; m0 += BM) {
        __syncthreads();
        if (tid < BM) {
            int idx = m0 + tid; bool v = idx < ne;
            if (sh) { toksS[tid] = v ? idx : (T_TOK - 1); twsS[tid] = 1.f; }
            else {
                toksS[tid] = v ? bucket_tok[base + idx] : bucket_tok[base];
                twsS[tid]  = v ? bucket_w[base + idx] : 0.f;
            }
        }
        __syncthreads();

        int asrc[4];
#pragma unroll
        for (int i = 0; i < 4; ++i) {
            int row = wid * 32 + i * 8 + (lane >> 3);
            asrc[i] = toksS[row] * H_DIM + (((lane & 7) ^ ASWZ(row)) << 3);
        }

        f32x4 acc[4][4];
#pragma unroll
        for (int i = 0; i < 4; ++i)
#pragma unroll
            for (int j = 0; j < 4; ++j) acc[i][j] = (f32x4){0.f, 0.f, 0.f, 0.f};

        // prologue: W(0)->regs->Bs[0]; W(1)->regs; GLDS A(0)->As[0]
        float4 bq[8];
#pragma unroll
        for (int j = 0; j < 8; ++j)
            bq[j] = *(const float4*)&W[(size_t)(kq + j) * (2 * F_DIM) + srccol];
#pragma unroll
        for (int cc = 0; cc < 4; ++cc) {
            short8v pk;
#pragma unroll
            for (int j = 0; j < 8; ++j)
                pk[j] = (short)f2bf(((const float*)&bq[j])[cc]);
            *(short8v*)&Bs[0][wrB[cc]] = pk;
        }
#pragma unroll
        for (int j = 0; j < 8; ++j)
            bq[j] = *(const float4*)&W[(size_t)(64 + kq + j) * (2 * F_DIM) + srccol];
#pragma unroll
        for (int i = 0; i < 4; ++i)
            GLDS16(xb + asrc[i], &As[0][(wid * 32 + i * 8) * 64]);
        __syncthreads();

        for (int kt = 0; kt < NT; ++kt) {
            const int k0 = kt * 64;
            if (kt + 1 < NT) {
#pragma unroll
                for (int i = 0; i < 4; ++i)
                    GLDS16(xb + asrc[i] + k0 + 64, &As[(kt + 1) & 1][(wid * 32 + i * 8) * 64]);
                unsigned short* nB = Bs[(kt + 1) & 1];
#pragma unroll
                for (int cc = 0; cc < 4; ++cc) {
                    short8v pk;
#pragma unroll
                    for (int j = 0; j < 8; ++j)
                        pk[j] = (short)f2bf(((const float*)&bq[j])[cc]);
                    *(short8v*)&nB[wrB[cc]] = pk;
                }
                int knx = (kt + 2 < NT) ? (k0 + 128) : (k0 + 64);
#pragma unroll
                for (int j = 0; j < 8; ++j)
                    bq[j] = *(const float4*)&W[(size_t)(knx + kq + j) * (2 * F_DIM) + srccol];
            }
            __builtin_amdgcn_sched_barrier(0);
            const unsigned short* A_ = As[kt & 1];
            const unsigned short* B_ = Bs[kt & 1];
#pragma unroll
            for (int ks = 0; ks < 2; ++ks) {
                short8v bf[4];
#pragma unroll
                for (int fn = 0; fn < 4; ++fn) bf[fn] = *(const short8v*)&B_[rdB[fn][ks]];
#pragma unroll
                for (int fm = 0; fm < 4; ++fm) {
                    short8v af = *(const short8v*)&A_[rdA[fm][ks]];
#pragma unroll
                    for (int fn = 0; fn < 4; ++fn)
                        acc[fm][fn] = __builtin_amdgcn_mfma_f32_16x16x32_bf16(
                            af, bf[fn], acc[fm][fn], 0, 0, 0);
                }
            }
            __syncthreads();
        }

        // epilogue: fn p = gate; fn p+2 = matching up
#pragma unroll
        for (int fm = 0; fm < 4; ++fm) {
#pragma unroll
            for (int p = 0; p < 2; ++p) {
                const int acol = c0 + wn * 32 + p * 16 + lrow;
#pragma unroll
                for (int i = 0; i < 4; ++i) {
                    int ml = wm * 64 + fm * 16 + lhi * 4 + i;
                    int idx = m0 + ml;
                    if (idx < ne) {
                        float gv = acc[fm][p][i], uv = acc[fm][p + 2][i];
                        float sg = gv / (1.f + __expf(-gv));
                        float val = sg * uv * twsS[ml];
                        if (sh) act_s[(size_t)idx * F_DIM + acol] = f2bf(val);
                        else    act_r[(size_t)(base + idx) * F_DIM + acol] = f2bf(val);
                    }
                }
            }
        }
    }
}

// ---------------------------------------------------------------------------
// down-proj — r14 structure, UNIFIED grid (eu<64 routed, eu>=64 shared m-tile).
// out pre-zeroed; ALL writes atomicAdd (order-free across routed/shared).
// BM=128, BN=128 out cols, BK=64 (8 phases).
// ---------------------------------------------------------------------------
__global__ __launch_bounds__(256, 2) void down_mfma_kernel(
    const unsigned short* __restrict__ act_r,
    const unsigned short* __restrict__ act_s,
    const float* __restrict__ Wd, const float* __restrict__ Wsd,
    const int* __restrict__ counts, const int* __restrict__ offsets,
    const int* __restrict__ bucket_tok, const float* __restrict__ sgate,
    float* __restrict__ out)
{
    constexpr int BM = 128;
    __shared__ __align__(16) unsigned short As[2][BM * 64];
    __shared__ __align__(16) unsigned short Bs[2][128 * 64];
    __shared__ int   toksS[BM];
    __shared__ float sgS[BM];

    const int tid  = threadIdx.x;
    const int lane = tid & 63;
    const int wid  = tid >> 6;
    const int wm = wid >> 1, wn = wid & 1;
    const int lrow = lane & 15, lhi = lane >> 4;

    // unified decode: 1280 blocks = 16 colblk x 80 eu
    const int nw  = (blockIdx.x & 7) * 160 + (blockIdx.x >> 3);
    const int cblk = nw & 15;
    const int eu   = nw >> 4;                 // 0..79
    const bool sh  = (eu >= E_NUM);
    int ne, base, m0_beg, m0_end;
    const float* W;
    const unsigned short* actb;
    if (sh) {
        ne = T_TOK; base = 0;
        m0_beg = (eu - E_NUM) * BM; m0_end = m0_beg + BM;
        W = Wsd; actb = act_s;
    } else {
        ne = counts[eu]; base = offsets[eu];
        m0_beg = 0; m0_end = ne;
        W = Wd + (size_t)eu * F_DIM * H_DIM; actb = act_r;
    }
    const int c0 = cblk * 128;

    const int n4 = (tid & 31) * 4;
    const int kq = (tid >> 5) * 8;
    const int srccol = c0 + n4;
    int wrB[4];
#pragma unroll
    for (int cc = 0; cc < 4; ++cc) {
        int n = n4 + cc;
        wrB[cc] = n * 64 + BCHUNK(n, kq >> 3) * 8;
    }
    int rdB[4][2];
#pragma unroll
    for (int fn = 0; fn < 4; ++fn) {
        int r = wn * 64 + fn * 16 + lrow;
#pragma unroll
        for (int ks = 0; ks < 2; ++ks) {
            int kc = ks * 4 + lhi;
            rdB[fn][ks] = r * 64 + BCHUNK(r, kc) * 8;
        }
    }
    int rdA[4][2];
#pragma unroll
    for (int fm = 0; fm < 4; ++fm) {
        int arow = wm * 64 + fm * 16 + lrow;
#pragma unroll
        for (int ks = 0; ks < 2; ++ks) {
            int kc = ks * 4 + lhi;
            rdA[fm][ks] = arow * 64 + ((kc ^ ASWZ(arow)) & 7) * 8;
        }
    }
    const int NT = F_DIM / 64;

    for (int m0 = m0_beg; m0 < m0_end; m0 += BM) {
        __syncthreads();
        if (tid < BM) {
            int idx = m0 + tid;
            if (sh) sgS[tid] = sgate[(idx < ne) ? idx : (T_TOK - 1)];
            else    toksS[tid] = (idx < ne) ? bucket_tok[base + idx] : 0;
        }
        __syncthreads();

        int asrc[4];
#pragma unroll
        for (int i = 0; i < 4; ++i) {
            int row = wid * 32 + i * 8 + (lane >> 3);
            int grow = sh ? min(m0 + row, T_TOK - 1)
                          : min(base + m0 + row, NROWS - 1);
            asrc[i] = grow * F_DIM + (((lane & 7) ^ ASWZ(row)) << 3);
        }

        f32x4 acc[4][4];
#pragma unroll
        for (int i = 0; i < 4; ++i)
#pragma unroll
            for (int j = 0; j < 4; ++j) acc[i][j] = (f32x4){0.f, 0.f, 0.f, 0.f};

        float4 bq[8];
#pragma unroll
        for (int j = 0; j < 8; ++j)
            bq[j] = *(const float4*)&W[(size_t)(kq + j) * H_DIM + srccol];
#pragma unroll
        for (int cc = 0; cc < 4; ++cc) {
            short8v pk;
#pragma unroll
            for (int j = 0; j < 8; ++j)
                pk[j] = (short)f2bf(((const float*)&bq[j])[cc]);
            *(short8v*)&Bs[0][wrB[cc]] = pk;
        }
#pragma unroll
        for (int j = 0; j < 8; ++j)
            bq[j] = *(const float4*)&W[(size_t)(64 + kq + j) * H_DIM + srccol];
#pragma unroll
        for (int i = 0; i < 4; ++i)
            GLDS16(actb + asrc[i], &As[0][(wid * 32 + i * 8) * 64]);
        __syncthreads();

        for (int kt = 0; kt < NT; ++kt) {
            const int k0 = kt * 64;
            if (kt + 1 < NT) {
#pragma unroll
                for (int i = 0; i < 4; ++i)
                    GLDS16(actb + asrc[i] + k0 + 64, &As[(kt + 1) & 1][(wid * 32 + i * 8) * 64]);
                unsigned short* nB = Bs[(kt + 1) & 1];
#pragma unroll
                for (int cc = 0; cc < 4; ++cc) {
                    short8v pk;
#pragma unroll
                    for (int j = 0; j < 8; ++j)
                        pk[j] = (short)f2bf(((const float*)&bq[j])[cc]);
                    *(short8v*)&nB[wrB[cc]] = pk;
                }
                int knx = (kt + 2 < NT) ? (k0 + 128) : (k0 + 64);
#pragma unroll
                for (int j = 0; j < 8; ++j)
                    bq[j] = *(const float4*)&W[(size_t)(knx + kq + j) * H_DIM + srccol];
            }
            __builtin_amdgcn_sched_barrier(0);
            const unsigned short* A_ = As[kt & 1];
            const unsigned short* B_ = Bs[kt & 1];
#pragma unroll
            for (int ks = 0; ks < 2; ++ks) {
                short8v bf[4];
#pragma unroll
                for (int fn = 0; fn < 4; ++fn) bf[fn] = *(const short8v*)&B_[rdB[fn][ks]];
#pragma unroll
                for (int fm = 0; fm < 4; ++fm) {
                    short8v af = *(const short8v*)&A_[rdA[fm][ks]];
#pragma unroll
                    for (int fn = 0; fn < 4; ++fn)
                        acc[fm][fn] = __builtin_amdgcn_mfma_f32_16x16x32_bf16(
                            af, bf[fn], acc[fm][fn], 0, 0, 0);
                }
            }
            __syncthreads();
        }

#pragma unroll
        for (int fm = 0; fm < 4; ++fm) {
#pragma unroll
            for (int fn = 0; fn < 4; ++fn) {
                int col = c0 + wn * 64 + fn * 16 + lrow;
#pragma unroll
                for (int i = 0; i < 4; ++i) {
                    int ml = wm * 64 + fm * 16 + lhi * 4 + i;
                    int idx = m0 + ml;
                    if (idx < ne) {
                        if (sh)
                            atomicAdd(&out[(size_t)idx * H_DIM + col], sgS[ml] * acc[fm][fn][i]);
                        else
                            atomicAdd(&out[(size_t)toksS[ml] * H_DIM + col], acc[fm][fn][i]);
                    }
                }
            }
        }
    }
}

// ---------------------------------------------------------------------------
extern "C" void kernel_launch(void* const* d_in, const int* in_sizes, int n_in,
                              void* d_out, int out_size, void* d_ws, size_t ws_size,
                              hipStream_t stream) {
    const float* x    = (const float*)d_in[0];
    const float* Wg   = (const float*)d_in[1];
    const float* Wgu  = (const float*)d_in[2];
    const float* Wd   = (const float*)d_in[3];
    const float* Wsgu = (const float*)d_in[4];
    const float* Wsd  = (const float*)d_in[5];
    float* out = (float*)d_out;

    char* p = (char*)d_ws;
    auto alloc = [&](size_t bytes) {
        char* r = p;
        p += (bytes + 255) & ~(size_t)255;
        return r;
    };
    int*   topk_idx   = (int*)  alloc((size_t)T_TOK * K_TOP * sizeof(int));
    float* topk_w     = (float*)alloc((size_t)T_TOK * K_TOP * sizeof(float));
    float* sgate      = (float*)alloc((size_t)T_TOK * sizeof(float));
    int*   counts     = (int*)  alloc((size_t)E_NUM * sizeof(int));
    int*   offsets    = (int*)  alloc((size_t)E_NUM * sizeof(int));
    int*   bucket_tok = (int*)  alloc((size_t)NROWS * sizeof(int));
    float* bucket_w   = (float*)alloc((size_t)NROWS * sizeof(float));
    unsigned short* xb    = (unsigned short*)alloc((size_t)T_TOK * H_DIM * 2);
    unsigned short* act_r = (unsigned short*)alloc((size_t)NROWS * F_DIM * 2);
    unsigned short* act_s = (unsigned short*)alloc((size_t)T_TOK * FS_DIM * 2);

    hipMemsetAsync(counts, 0, E_NUM * sizeof(int), stream);
    hipMemsetAsync(out, 0, (size_t)T_TOK * H_DIM * sizeof(float), stream);
    cvt_bf16_kernel<<<(T_TOK * H_DIM / 8 + 255) / 256, 256, 0, stream>>>(x, xb, T_TOK * H_DIM / 8);
    router_kernel<<<T_TOK, 64, 0, stream>>>(x, Wg, topk_idx, topk_w, sgate, counts);
    bucket_kernel<<<E_NUM, 256, 0, stream>>>(topk_idx, topk_w, counts, offsets, bucket_tok, bucket_w);

    // unified gate_up: 8 colblks x (64 routed experts + 16 shared m-tiles)
    gu_mfma_kernel<<<8 * 80, 256, 0, stream>>>(
        xb, Wgu, Wsgu, counts, offsets, bucket_tok, bucket_w, act_r, act_s);

    // unified down: 16 colblks x (64 routed + 16 shared m-tiles), all atomic
    down_mfma_kernel<<<16 * 80, 256, 0, stream>>>(
        act_r, act_s, Wd, Wsd, counts, offsets, bucket_tok, sgate, out);
}

// Round 22
// 705.131 us; speedup vs baseline: 1.0745x; 1.0745x over previous
//
#include <hip/hip_runtime.h>
#include <hip/hip_bf16.h>
#include <math.h>

#define T_TOK 2048
#define H_DIM 2048
#define E_NUM 64
#define F_DIM 512
#define K_TOP 8
#define FS_DIM 512
#define NROWS (T_TOK * K_TOP)

typedef __attribute__((ext_vector_type(8))) short short8v;   // bf16x8 MFMA frag
typedef __attribute__((ext_vector_type(4))) float f32x4;     // MFMA accum

static __device__ __forceinline__ unsigned short f2bf(float f) {
    unsigned int u = __float_as_uint(f);
    u += 0x7fff + ((u >> 16) & 1);           // RNE to bf16
    return (unsigned short)(u >> 16);
}

// B tile [128 n][64 k]: 16B-chunk XOR swizzle (proven r5/6/9-14)
#define BCHUNK(row, k8) ((((k8) ^ ((row) + ((row) >> 3)))) & 7)
// A tile rows 64 shorts (128B, bank-neutral): 8-chunk XOR (proven r9)
#define ASWZ(row) (((row) + ((row) >> 3)) & 7)

typedef const unsigned int __attribute__((address_space(1))) gu32;
typedef unsigned int __attribute__((address_space(3))) lu32;
#define GLDS16(gsrc, ldst) \
    __builtin_amdgcn_global_load_lds((gu32*)(gsrc), (lu32*)(ldst), 16, 0, 0)

// ---------------------------------------------------------------------------
// x (fp32) -> bf16 copy
// ---------------------------------------------------------------------------
__global__ __launch_bounds__(256) void cvt_bf16_kernel(
    const float* __restrict__ in, unsigned short* __restrict__ out, int n8)
{
    int i = blockIdx.x * 256 + threadIdx.x;
    if (i < n8) {
        const float4* p = (const float4*)(in + (size_t)i * 8);
        float4 v0 = p[0], v1 = p[1];
        ushort4 a = make_ushort4(f2bf(v0.x), f2bf(v0.y), f2bf(v0.z), f2bf(v0.w));
        ushort4 b = make_ushort4(f2bf(v1.x), f2bf(v1.y), f2bf(v1.z), f2bf(v1.w));
        ushort4* q = (ushort4*)(out + (size_t)i * 8);
        q[0] = a; q[1] = b;
    }
}

// ---------------------------------------------------------------------------
// Router: one wave per token (fp32 math, exact top-k vs reference).
// ---------------------------------------------------------------------------
__global__ __launch_bounds__(64) void router_kernel(
    const float* __restrict__ x, const float* __restrict__ Wg,
    int* __restrict__ topk_idx, float* __restrict__ topk_w,
    float* __restrict__ sgate, int* __restrict__ counts)
{
    const int t = blockIdx.x;
    const int lane = threadIdx.x;
    const float* xr = x + (size_t)t * H_DIM;

    float a0 = 0.f, a1 = 0.f, a2 = 0.f, a3 = 0.f;
    for (int h = 0; h < H_DIM; h += 4) {
        float4 xv = *(const float4*)&xr[h];
        a0 += xv.x * Wg[(h + 0) * 65 + lane];
        a1 += xv.y * Wg[(h + 1) * 65 + lane];
        a2 += xv.z * Wg[(h + 2) * 65 + lane];
        a3 += xv.w * Wg[(h + 3) * 65 + lane];
    }
    float logit = (a0 + a1) + (a2 + a3);

    float a64 = 0.f;
    for (int h = lane; h < H_DIM; h += 64) a64 += xr[h] * Wg[h * 65 + 64];
#pragma unroll
    for (int off = 32; off >= 1; off >>= 1) a64 += __shfl_xor(a64, off);

    float v = logit;
    float selv[K_TOP]; int seli[K_TOP];
#pragma unroll
    for (int k = 0; k < K_TOP; ++k) {
        float mv = v; int mi = lane;
#pragma unroll
        for (int off = 32; off >= 1; off >>= 1) {
            float ov = __shfl_xor(mv, off);
            int   oi = __shfl_xor(mi, off);
            if (ov > mv || (ov == mv && oi < mi)) { mv = ov; mi = oi; }
        }
        selv[k] = mv; seli[k] = mi;
        if (lane == mi) v = -INFINITY;
    }

    if (lane == 0) {
        float m = selv[0];
        float w[K_TOP]; float s = 0.f;
#pragma unroll
        for (int k = 0; k < K_TOP; ++k) { w[k] = __expf(selv[k] - m); s += w[k]; }
        float inv = 1.f / s;
#pragma unroll
        for (int k = 0; k < K_TOP; ++k) {
            topk_idx[t * K_TOP + k] = seli[k];
            topk_w[t * K_TOP + k] = w[k] * inv;
            atomicAdd(&counts[seli[k]], 1);
        }
        sgate[t] = 1.f / (1.f + __expf(-a64));
    }
}

// ---------------------------------------------------------------------------
// Deterministic per-expert compaction.
// ---------------------------------------------------------------------------
__global__ __launch_bounds__(256) void bucket_kernel(
    const int* __restrict__ topk_idx, const float* __restrict__ topk_w,
    const int* __restrict__ counts, int* __restrict__ offsets,
    int* __restrict__ bucket_tok, float* __restrict__ bucket_w)
{
    const int e = blockIdx.x, thr = threadIdx.x;
    __shared__ int cnt[256];
    __shared__ int base_s;
    const int q0 = thr * 64;
    int c = 0;
    for (int q = 0; q < 64; ++q) c += (topk_idx[q0 + q] == e) ? 1 : 0;
    cnt[thr] = c;
    __syncthreads();
    if (thr == 0) {
        int off = 0;
        for (int i = 0; i < e; ++i) off += counts[i];
        offsets[e] = off;
        base_s = off;
        int run = 0;
        for (int i = 0; i < 256; ++i) { int tval = cnt[i]; cnt[i] = run; run += tval; }
    }
    __syncthreads();
    int pos = base_s + cnt[thr];
    for (int q = 0; q < 64; ++q) {
        int pp = q0 + q;
        if (topk_idx[pp] == e) {
            bucket_tok[pos] = pp >> 3;
            bucket_w[pos] = topk_w[pp];
            ++pos;
        }
    }
}

// ---------------------------------------------------------------------------
// gate_up + SiLU*u*topw — FAT-PHASE 2-stage pipeline. BM=128, BK=64 phases,
// 256 thr = 4 waves (2wm x 2wn), wave = 64 rows x 64 W-cols -> 32 MFMA/phase.
// A: gathered x rows via GLDS dbuf [2][128][64] (r9-proven swizzle).
// B: W fp32 -> reg -> bf16 -> b128 ds_write dbuf [2][128][64] (r11 BCHUNK).
// Phase t: GLDS A(t+1); write B(t+1) from regs; load W(t+2)->regs;
//          compute(t); __syncthreads (full drain, memory-safe).
// W-col layout per block: [g c0..c0+31 | u c0..c0+31 | g c0+32.. | u c0+32..].
// ---------------------------------------------------------------------------
template<bool ROUTED>
__global__ __launch_bounds__(256, 2) void gu_mfma_kernel(
    const unsigned short* __restrict__ xb,
    const float* __restrict__ Wall,
    const int* __restrict__ counts, const int* __restrict__ offsets,
    const int* __restrict__ bucket_tok, const float* __restrict__ bucket_w,
    unsigned short* __restrict__ actout)
{
    constexpr int BM = 128;
    __shared__ __align__(16) unsigned short As[2][BM * 64];   // 2 x 16 KB
    __shared__ __align__(16) unsigned short Bs[2][128 * 64];  // 2 x 16 KB
    __shared__ int   toksS[BM];
    __shared__ float twsS[BM];

    const int tid  = threadIdx.x;
    const int lane = tid & 63;
    const int wid  = tid >> 6;                // 0..3
    const int wm = wid >> 1, wn = wid & 1;
    const int lrow = lane & 15, lhi = lane >> 4;

    int cblk, ne, base;
    const float* W;
    if (ROUTED) {
        int nw = (blockIdx.x & 7) * ((int)gridDim.x >> 3) + (blockIdx.x >> 3);
        int e = nw >> 3; cblk = nw & 7;
        ne = counts[e]; base = offsets[e];
        W = Wall + (size_t)e * H_DIM * (2 * F_DIM);
    } else {
        cblk = blockIdx.x;
        ne = T_TOK; base = 0;
        W = Wall;
    }
    const int c0 = cblk * 64;                 // act-col base (64 per block)

    // B staging: thread covers 4 n-cols x 8 k-rows
    const int n4 = (tid & 31) * 4;            // 0..124
    const int kq = (tid >> 5) * 8;            // 0..56
    const int grp = n4 >> 5;                  // 0..3 -> {g lo,u lo,g hi,u hi}
    const int srccol = c0 + (grp >> 1) * 32 + (n4 & 31) + ((grp & 1) ? F_DIM : 0);
    int wrB[4];
#pragma unroll
    for (int cc = 0; cc < 4; ++cc) {
        int n = n4 + cc;
        wrB[cc] = n * 64 + BCHUNK(n, kq >> 3) * 8;
    }
    // B frag read offsets: rows r = wn*64 + fn*16 + lrow
    int rdB[4][2];
#pragma unroll
    for (int fn = 0; fn < 4; ++fn) {
        int r = wn * 64 + fn * 16 + lrow;
#pragma unroll
        for (int ks = 0; ks < 2; ++ks) {
            int kc = ks * 4 + lhi;
            rdB[fn][ks] = r * 64 + BCHUNK(r, kc) * 8;
        }
    }
    // A frag read offsets: rows arow = wm*64 + fm*16 + lrow
    int rdA[4][2];
#pragma unroll
    for (int fm = 0; fm < 4; ++fm) {
        int arow = wm * 64 + fm * 16 + lrow;
#pragma unroll
        for (int ks = 0; ks < 2; ++ks) {
            int kc = ks * 4 + lhi;
            rdA[fm][ks] = arow * 64 + ((kc ^ ASWZ(arow)) & 7) * 8;
        }
    }
    // A staging: wave stages rows [wid*32, wid*32+32); issue i covers 8 rows
    const int NT = H_DIM / 64;

    const int m0_beg = ROUTED ? 0 : blockIdx.y * BM;
    const int m0_end = ROUTED ? ne : m0_beg + BM;

    for (int m0 = m0_beg; m0 < m0_end; m0 += BM) {
        __syncthreads();
        if (tid < BM) {
            int idx = m0 + tid; bool v = idx < ne;
            if (ROUTED) {
                toksS[tid] = v ? bucket_tok[base + idx] : bucket_tok[base];
                twsS[tid]  = v ? bucket_w[base + idx] : 0.f;
            } else {
                toksS[tid] = v ? idx : (T_TOK - 1);
                twsS[tid]  = 1.f;
            }
        }
        __syncthreads();

        // per-lane A-source element offsets for the 4 staging issues
        int asrc[4];
#pragma unroll
        for (int i = 0; i < 4; ++i) {
            int row = wid * 32 + i * 8 + (lane >> 3);
            asrc[i] = toksS[row] * H_DIM + (((lane & 7) ^ ASWZ(row)) << 3);
        }

        f32x4 acc[4][4];
#pragma unroll
        for (int i = 0; i < 4; ++i)
#pragma unroll
            for (int j = 0; j < 4; ++j) acc[i][j] = (f32x4){0.f, 0.f, 0.f, 0.f};

        // prologue: W(0)->regs->Bs[0]; W(1)->regs; GLDS A(0)->As[0]
        float4 bq[8];
#pragma unroll
        for (int j = 0; j < 8; ++j)
            bq[j] = *(const float4*)&W[(size_t)(kq + j) * (2 * F_DIM) + srccol];
#pragma unroll
        for (int cc = 0; cc < 4; ++cc) {
            short8v pk;
#pragma unroll
            for (int j = 0; j < 8; ++j)
                pk[j] = (short)f2bf(((const float*)&bq[j])[cc]);
            *(short8v*)&Bs[0][wrB[cc]] = pk;
        }
#pragma unroll
        for (int j = 0; j < 8; ++j)
            bq[j] = *(const float4*)&W[(size_t)(64 + kq + j) * (2 * F_DIM) + srccol];
#pragma unroll
        for (int i = 0; i < 4; ++i)
            GLDS16(xb + asrc[i], &As[0][(wid * 32 + i * 8) * 64]);
        __syncthreads();

        for (int kt = 0; kt < NT; ++kt) {
            const int k0 = kt * 64;
            // stage tile kt+1
            if (kt + 1 < NT) {
#pragma unroll
                for (int i = 0; i < 4; ++i)
                    GLDS16(xb + asrc[i] + k0 + 64, &As[(kt + 1) & 1][(wid * 32 + i * 8) * 64]);
                unsigned short* nB = Bs[(kt + 1) & 1];
#pragma unroll
                for (int cc = 0; cc < 4; ++cc) {
                    short8v pk;
#pragma unroll
                    for (int j = 0; j < 8; ++j)
                        pk[j] = (short)f2bf(((const float*)&bq[j])[cc]);
                    *(short8v*)&nB[wrB[cc]] = pk;
                }
                int knx = (kt + 2 < NT) ? (k0 + 128) : (k0 + 64);
#pragma unroll
                for (int j = 0; j < 8; ++j)
                    bq[j] = *(const float4*)&W[(size_t)(knx + kq + j) * (2 * F_DIM) + srccol];
            }
            __builtin_amdgcn_sched_barrier(0);
            // compute tile kt: 32 MFMA per wave
            const unsigned short* A_ = As[kt & 1];
            const unsigned short* B_ = Bs[kt & 1];
#pragma unroll
            for (int ks = 0; ks < 2; ++ks) {
                short8v bf[4];
#pragma unroll
                for (int fn = 0; fn < 4; ++fn) bf[fn] = *(const short8v*)&B_[rdB[fn][ks]];
#pragma unroll
                for (int fm = 0; fm < 4; ++fm) {
                    short8v af = *(const short8v*)&A_[rdA[fm][ks]];
#pragma unroll
                    for (int fn = 0; fn < 4; ++fn)
                        acc[fm][fn] = __builtin_amdgcn_mfma_f32_16x16x32_bf16(
                            af, bf[fn], acc[fm][fn], 0, 0, 0);
                }
            }
            __syncthreads();
        }

        // epilogue: fn 0,1 = gate; fn+2 = matching up; acol = c0+wn*32+fn*16+lrow
#pragma unroll
        for (int fm = 0; fm < 4; ++fm) {
#pragma unroll
            for (int p = 0; p < 2; ++p) {
                const int acol = c0 + wn * 32 + p * 16 + lrow;
#pragma unroll
                for (int i = 0; i < 4; ++i) {
                    int ml = wm * 64 + fm * 16 + lhi * 4 + i;
                    int idx = m0 + ml;
                    if (idx < ne) {
                        float gv = acc[fm][p][i], uv = acc[fm][p + 2][i];
                        float sg = gv / (1.f + __expf(-gv));
                        float val = sg * uv * twsS[ml];
                        size_t orow = ROUTED ? (size_t)(base + idx) : (size_t)idx;
                        actout[orow * F_DIM + acol] = f2bf(val);
                    }
                }
            }
        }
    }
}

// ---------------------------------------------------------------------------
// down-proj — same fat-phase structure. BM=128, BN=128 out cols, BK=64
// (8 phases). A = packed act rows; B = Wd[k][H] slice.
// ROUTED: atomicAdd scatter; shared: plain store * sigmoid.
// ---------------------------------------------------------------------------
template<bool ROUTED>
__global__ __launch_bounds__(256, 2) void down_mfma_kernel(
    const unsigned short* __restrict__ actb,
    const float* __restrict__ Wall,
    const int* __restrict__ counts, const int* __restrict__ offsets,
    const int* __restrict__ bucket_tok, const float* __restrict__ sgate,
    float* __restrict__ out)
{
    constexpr int BM = 128;
    __shared__ __align__(16) unsigned short As[2][BM * 64];
    __shared__ __align__(16) unsigned short Bs[2][128 * 64];
    __shared__ int   toksS[BM];
    __shared__ float sgS[BM];

    const int tid  = threadIdx.x;
    const int lane = tid & 63;
    const int wid  = tid >> 6;
    const int wm = wid >> 1, wn = wid & 1;
    const int lrow = lane & 15, lhi = lane >> 4;

    int cblk, ne, base;
    const float* W;
    if (ROUTED) {
        int nw = (blockIdx.x & 7) * ((int)gridDim.x >> 3) + (blockIdx.x >> 3);
        int e = nw >> 4; cblk = nw & 15;
        ne = counts[e]; base = offsets[e];
        W = Wall + (size_t)e * F_DIM * H_DIM;
    } else {
        cblk = blockIdx.x;
        ne = T_TOK; base = 0;
        W = Wall;
    }
    const int c0 = cblk * 128;

    const int n4 = (tid & 31) * 4;
    const int kq = (tid >> 5) * 8;
    const int srccol = c0 + n4;
    int wrB[4];
#pragma unroll
    for (int cc = 0; cc < 4; ++cc) {
        int n = n4 + cc;
        wrB[cc] = n * 64 + BCHUNK(n, kq >> 3) * 8;
    }
    int rdB[4][2];
#pragma unroll
    for (int fn = 0; fn < 4; ++fn) {
        int r = wn * 64 + fn * 16 + lrow;
#pragma unroll
        for (int ks = 0; ks < 2; ++ks) {
            int kc = ks * 4 + lhi;
            rdB[fn][ks] = r * 64 + BCHUNK(r, kc) * 8;
        }
    }
    int rdA[4][2];
#pragma unroll
    for (int fm = 0; fm < 4; ++fm) {
        int arow = wm * 64 + fm * 16 + lrow;
#pragma unroll
        for (int ks = 0; ks < 2; ++ks) {
            int kc = ks * 4 + lhi;
            rdA[fm][ks] = arow * 64 + ((kc ^ ASWZ(arow)) & 7) * 8;
        }
    }
    const int NT = F_DIM / 64;

    const int m0_beg = ROUTED ? 0 : blockIdx.y * BM;
    const int m0_end = ROUTED ? ne : m0_beg + BM;

    for (int m0 = m0_beg; m0 < m0_end; m0 += BM) {
        __syncthreads();
        if (tid < BM) {
            int idx = m0 + tid;
            if (ROUTED) {
                toksS[tid] = (idx < ne) ? bucket_tok[base + idx] : 0;
            } else {
                sgS[tid] = sgate[(idx < ne) ? idx : (T_TOK - 1)];
            }
        }
        __syncthreads();

        int asrc[4];
#pragma unroll
        for (int i = 0; i < 4; ++i) {
            int row = wid * 32 + i * 8 + (lane >> 3);
            int grow = ROUTED ? min(base + m0 + row, NROWS - 1)
                              : min(m0 + row, T_TOK - 1);
            asrc[i] = grow * F_DIM + (((lane & 7) ^ ASWZ(row)) << 3);
        }

        f32x4 acc[4][4];
#pragma unroll
        for (int i = 0; i < 4; ++i)
#pragma unroll
            for (int j = 0; j < 4; ++j) acc[i][j] = (f32x4){0.f, 0.f, 0.f, 0.f};

        float4 bq[8];
#pragma unroll
        for (int j = 0; j < 8; ++j)
            bq[j] = *(const float4*)&W[(size_t)(kq + j) * H_DIM + srccol];
#pragma unroll
        for (int cc = 0; cc < 4; ++cc) {
            short8v pk;
#pragma unroll
            for (int j = 0; j < 8; ++j)
                pk[j] = (short)f2bf(((const float*)&bq[j])[cc]);
            *(short8v*)&Bs[0][wrB[cc]] = pk;
        }
#pragma unroll
        for (int j = 0; j < 8; ++j)
            bq[j] = *(const float4*)&W[(size_t)(64 + kq + j) * H_DIM + srccol];
#pragma unroll
        for (int i = 0; i < 4; ++i)
            GLDS16(actb + asrc[i], &As[0][(wid * 32 + i * 8) * 64]);
        __syncthreads();

        for (int kt = 0; kt < NT; ++kt) {
            const int k0 = kt * 64;
            if (kt + 1 < NT) {
#pragma unroll
                for (int i = 0; i < 4; ++i)
                    GLDS16(actb + asrc[i] + k0 + 64, &As[(kt + 1) & 1][(wid * 32 + i * 8) * 64]);
                unsigned short* nB = Bs[(kt + 1) & 1];
#pragma unroll
                for (int cc = 0; cc < 4; ++cc) {
                    short8v pk;
#pragma unroll
                    for (int j = 0; j < 8; ++j)
                        pk[j] = (short)f2bf(((const float*)&bq[j])[cc]);
                    *(short8v*)&nB[wrB[cc]] = pk;
                }
                int knx = (kt + 2 < NT) ? (k0 + 128) : (k0 + 64);
#pragma unroll
                for (int j = 0; j < 8; ++j)
                    bq[j] = *(const float4*)&W[(size_t)(knx + kq + j) * H_DIM + srccol];
            }
            __builtin_amdgcn_sched_barrier(0);
            const unsigned short* A_ = As[kt & 1];
            const unsigned short* B_ = Bs[kt & 1];
#pragma unroll
            for (int ks = 0; ks < 2; ++ks) {
                short8v bf[4];
#pragma unroll
                for (int fn = 0; fn < 4; ++fn) bf[fn] = *(const short8v*)&B_[rdB[fn][ks]];
#pragma unroll
                for (int fm = 0; fm < 4; ++fm) {
                    short8v af = *(const short8v*)&A_[rdA[fm][ks]];
#pragma unroll
                    for (int fn = 0; fn < 4; ++fn)
                        acc[fm][fn] = __builtin_amdgcn_mfma_f32_16x16x32_bf16(
                            af, bf[fn], acc[fm][fn], 0, 0, 0);
                }
            }
            __syncthreads();
        }

#pragma unroll
        for (int fm = 0; fm < 4; ++fm) {
#pragma unroll
            for (int fn = 0; fn < 4; ++fn) {
                int col = c0 + wn * 64 + fn * 16 + lrow;
#pragma unroll
                for (int i = 0; i < 4; ++i) {
                    int ml = wm * 64 + fm * 16 + lhi * 4 + i;
                    int idx = m0 + ml;
                    if (idx < ne) {
                        if (ROUTED)
                            atomicAdd(&out[(size_t)toksS[ml] * H_DIM + col], acc[fm][fn][i]);
                        else
                            out[(size_t)idx * H_DIM + col] = sgS[ml] * acc[fm][fn][i];
                    }
                }
            }
        }
    }
}

// ---------------------------------------------------------------------------
extern "C" void kernel_launch(void* const* d_in, const int* in_sizes, int n_in,
                              void* d_out, int out_size, void* d_ws, size_t ws_size,
                              hipStream_t stream) {
    const float* x    = (const float*)d_in[0];
    const float* Wg   = (const float*)d_in[1];
    const float* Wgu  = (const float*)d_in[2];
    const float* Wd   = (const float*)d_in[3];
    const float* Wsgu = (const float*)d_in[4];
    const float* Wsd  = (const float*)d_in[5];
    float* out = (float*)d_out;

    char* p = (char*)d_ws;
    auto alloc = [&](size_t bytes) {
        char* r = p;
        p += (bytes + 255) & ~(size_t)255;
        return r;
    };
    int*   topk_idx   = (int*)  alloc((size_t)T_TOK * K_TOP * sizeof(int));
    float* topk_w     = (float*)alloc((size_t)T_TOK * K_TOP * sizeof(float));
    float* sgate      = (float*)alloc((size_t)T_TOK * sizeof(float));
    int*   counts     = (int*)  alloc((size_t)E_NUM * sizeof(int));
    int*   offsets    = (int*)  alloc((size_t)E_NUM * sizeof(int));
    int*   bucket_tok = (int*)  alloc((size_t)NROWS * sizeof(int));
    float* bucket_w   = (float*)alloc((size_t)NROWS * sizeof(float));
    unsigned short* xb    = (unsigned short*)alloc((size_t)T_TOK * H_DIM * 2);
    unsigned short* act_r = (unsigned short*)alloc((size_t)NROWS * F_DIM * 2);
    unsigned short* act_s = (unsigned short*)alloc((size_t)T_TOK * FS_DIM * 2);

    hipMemsetAsync(counts, 0, E_NUM * sizeof(int), stream);
    cvt_bf16_kernel<<<(T_TOK * H_DIM / 8 + 255) / 256, 256, 0, stream>>>(x, xb, T_TOK * H_DIM / 8);
    router_kernel<<<T_TOK, 64, 0, stream>>>(x, Wg, topk_idx, topk_w, sgate, counts);
    bucket_kernel<<<E_NUM, 256, 0, stream>>>(topk_idx, topk_w, counts, offsets, bucket_tok, bucket_w);

    // routed gate_up: 8 colblks x 64 experts (in-block m-loop), XCD-swizzled
    gu_mfma_kernel<true><<<8 * E_NUM, 256, 0, stream>>>(
        xb, Wgu, counts, offsets, bucket_tok, bucket_w, act_r);
    // shared gate_up: 8 colblks x 16 m-tiles
    gu_mfma_kernel<false><<<dim3(8, T_TOK / 128), 256, 0, stream>>>(
        xb, Wsgu, counts, offsets, bucket_tok, bucket_w, act_s);

    // shared down writes out first; routed down accumulates atomically on top
    down_mfma_kernel<false><<<dim3(16, T_TOK / 128), 256, 0, stream>>>(
        act_s, Wsd, counts, offsets, bucket_tok, sgate, out);
    down_mfma_kernel<true><<<16 * E_NUM, 256, 0, stream>>>(
        act_r, Wd, counts, offsets, bucket_tok, sgate, out);
}